// Round 5
// baseline (355.121 us; speedup 1.0000x reference)
//
#include <hip/hip_runtime.h>

typedef __attribute__((ext_vector_type(8))) short short8;
typedef __attribute__((ext_vector_type(4))) float f32x4;

#define DIM_C 1024
#define NHEAD 16
#define HDIM  64
#define BB    2
#define TT    2048
#define NELEM ((size_t)BB * NHEAD * TT * HDIM)   // 4194304 per tensor

// ---- bf16 helpers (bit-level, RNE) ----------------------------------------
__device__ __forceinline__ short f2b(float f) {
    union { float f; unsigned u; } c; c.f = f;
    unsigned r = c.u + 0x7FFFu + ((c.u >> 16) & 1u);
    return (short)(r >> 16);
}
__device__ __forceinline__ float b2f(short s) {
    union { unsigned u; float f; } c; c.u = ((unsigned)(unsigned short)s) << 16;
    return c.f;
}
__device__ __forceinline__ void gload_lds16(const short* g, short* l) {
    __builtin_amdgcn_global_load_lds(
        (const __attribute__((address_space(1))) unsigned int*)g,
        (__attribute__((address_space(3))) unsigned int*)l, 16, 0, 0);
}

// ---------------------------------------------------------------------------
// Pre-pass 1: elementwise fp32 -> split bf16 (hi + lo)
// ---------------------------------------------------------------------------
__global__ __launch_bounds__(256) void split_f32(const float* __restrict__ X,
                                                 short* __restrict__ H,
                                                 short* __restrict__ L, int n4)
{
    const int i = blockIdx.x * 256 + threadIdx.x;
    if (i >= n4) return;
    float4 v = ((const float4*)X)[i];
    short h0 = f2b(v.x), h1 = f2b(v.y), h2 = f2b(v.z), h3 = f2b(v.w);
    short l0 = f2b(v.x - b2f(h0)), l1 = f2b(v.y - b2f(h1));
    short l2 = f2b(v.z - b2f(h2)), l3 = f2b(v.w - b2f(h3));
    typedef __attribute__((ext_vector_type(4))) short short4v;
    ((short4v*)H)[i] = (short4v){h0, h1, h2, h3};
    ((short4v*)L)[i] = (short4v){l0, l1, l2, l3};
}

// ---------------------------------------------------------------------------
// Pre-pass 2: W (K x N) fp32 -> W^T (N x K) split bf16, 32x32 LDS transpose
// ---------------------------------------------------------------------------
__global__ __launch_bounds__(256) void transpose_split(const float* __restrict__ W,
                                                       short* __restrict__ Th,
                                                       short* __restrict__ Tl,
                                                       int K, int N)
{
    __shared__ float T[32][33];
    const int tx = threadIdx.x & 31, ty = threadIdx.x >> 5;   // 32 x 8
    const int n0 = blockIdx.x * 32, k0 = blockIdx.y * 32;
#pragma unroll
    for (int i = 0; i < 4; ++i)
        T[ty + i * 8][tx] = W[(size_t)(k0 + ty + i * 8) * N + n0 + tx];
    __syncthreads();
#pragma unroll
    for (int i = 0; i < 4; ++i) {
        const int n = ty + i * 8;
        const float v = T[tx][n];
        const short hi = f2b(v);
        Th[(size_t)(n0 + n) * K + k0 + tx] = hi;
        Tl[(size_t)(n0 + n) * K + k0 + tx] = f2b(v - b2f(hi));
    }
}

// ---------------------------------------------------------------------------
// Split-bf16 MFMA GEMM v2: counted-vmcnt double-buffered pipeline.
// 128x128 tile, BK=32, 512 thr = 8 waves (2 row-groups x 4 col-groups),
// wave tile 64x32. LDS 64 KB (4 arrays x dbuf x 8 KB) -> 2 blocks/CU.
// Pipeline: prologue stages tiles 0,1; iter t waits vmcnt(4) (tile t done,
// tile t+1 in flight), computes, then stages t+2 into the freed buffer.
// vmcnt never drains to 0 in the main loop (T4); setprio around MFMA (T5).
// ---------------------------------------------------------------------------
template <int EPI>
__global__ __launch_bounds__(512, 4) void gemm_mfma(
    const short* __restrict__ Ah, const short* __restrict__ Al,
    const short* __restrict__ BTh, const short* __restrict__ BTl,
    const float* __restrict__ bias,
    float* __restrict__ outF,
    short* __restrict__ qh_, short* __restrict__ ql_,
    short* __restrict__ kh_, short* __restrict__ kl_,
    short* __restrict__ vh_, short* __restrict__ vl_,
    int M, int N, int K)
{
    __shared__ short As_h[2][128 * 32];
    __shared__ short As_l[2][128 * 32];
    __shared__ short Bs_h[2][128 * 32];
    __shared__ short Bs_l[2][128 * 32];

    const int tid  = threadIdx.x;
    const int lane = tid & 63;
    const int wid  = tid >> 6;
    const int wr   = wid >> 2;          // 0..1 : rows [wr*64, +64)
    const int wc   = wid & 3;           // 0..3 : cols [wc*32, +32)
    const int g    = lane >> 4, lr = lane & 15;
    const int row0 = blockIdx.y * 128;
    const int col0 = blockIdx.x * 128;
    const int KT   = K >> 5;            // number of BK=32 tiles

    // staging map: thread -> one 16B chunk per array. 512 chunks = 128 rows x 4.
    const int sr  = tid >> 2;                       // row 0..127
    const int ss  = (tid & 3) ^ ((sr >> 1) & 3);    // pre-swizzled source slot
    const size_t srcAb = (size_t)(row0 + sr) * K + ss * 8;
    const size_t srcBb = (size_t)(col0 + sr) * K + ss * 8;

    auto STAGE = [&](int kt, int b) {
        const size_t ka = srcAb + kt * 32;
        const size_t kb = srcBb + kt * 32;
        gload_lds16(Ah + ka, &As_h[b][tid * 8]);
        gload_lds16(Al + ka, &As_l[b][tid * 8]);
        gload_lds16(BTh + kb, &Bs_h[b][tid * 8]);
        gload_lds16(BTl + kb, &Bs_l[b][tid * 8]);
    };

    f32x4 acc[4][2];
#pragma unroll
    for (int m = 0; m < 4; ++m)
#pragma unroll
        for (int n = 0; n < 2; ++n) acc[m][n] = (f32x4){0.f, 0.f, 0.f, 0.f};

    STAGE(0, 0);
    STAGE(1, 1);

    for (int t = 0; t < KT; ++t) {
        const int c = t & 1;
        if (t == KT - 1) { asm volatile("s_waitcnt vmcnt(0)" ::: "memory"); }
        else             { asm volatile("s_waitcnt vmcnt(4)" ::: "memory"); }
        __builtin_amdgcn_sched_barrier(0);
        __builtin_amdgcn_s_barrier();
        __builtin_amdgcn_sched_barrier(0);

        short8 bhf[2], blf[2];
#pragma unroll
        for (int mh = 0; mh < 2; ++mh) {
            if (mh == 0) {
#pragma unroll
                for (int n = 0; n < 2; ++n) {
                    const int r  = wc * 32 + n * 16 + lr;
                    const int sl = g ^ ((r >> 1) & 3);
                    bhf[n] = *(const short8*)&Bs_h[c][r * 32 + sl * 8];
                    blf[n] = *(const short8*)&Bs_l[c][r * 32 + sl * 8];
                }
            }
            short8 ahf[2], alf[2];
#pragma unroll
            for (int m2 = 0; m2 < 2; ++m2) {
                const int r  = wr * 64 + (mh * 2 + m2) * 16 + lr;
                const int sl = g ^ ((r >> 1) & 3);
                ahf[m2] = *(const short8*)&As_h[c][r * 32 + sl * 8];
                alf[m2] = *(const short8*)&As_l[c][r * 32 + sl * 8];
            }
            asm volatile("s_waitcnt lgkmcnt(0)" ::: "memory");
            __builtin_amdgcn_sched_barrier(0);
            __builtin_amdgcn_s_setprio(1);
#pragma unroll
            for (int m2 = 0; m2 < 2; ++m2)
#pragma unroll
                for (int n = 0; n < 2; ++n) {
                    const int m = mh * 2 + m2;
                    acc[m][n] = __builtin_amdgcn_mfma_f32_16x16x32_bf16(ahf[m2], bhf[n], acc[m][n], 0, 0, 0);
                    acc[m][n] = __builtin_amdgcn_mfma_f32_16x16x32_bf16(alf[m2], bhf[n], acc[m][n], 0, 0, 0);
                    acc[m][n] = __builtin_amdgcn_mfma_f32_16x16x32_bf16(ahf[m2], blf[n], acc[m][n], 0, 0, 0);
                }
            __builtin_amdgcn_s_setprio(0);
            __builtin_amdgcn_sched_barrier(0);
            __builtin_amdgcn_s_barrier();
            __builtin_amdgcn_sched_barrier(0);
        }
        if (t + 2 < KT) STAGE(t + 2, c);
    }

    // --- epilogue ---
#pragma unroll
    for (int m = 0; m < 4; ++m) {
#pragma unroll
        for (int n = 0; n < 2; ++n) {
#pragma unroll
            for (int r = 0; r < 4; ++r) {
                const int grow = row0 + wr * 64 + m * 16 + g * 4 + r;
                const int gcol = col0 + wc * 32 + n * 16 + lr;
                const float vv = acc[m][n][r] + bias[gcol];
                if (EPI == 0) {
                    const int b     = grow / TT;
                    const int t     = grow % TT;
                    const int which = gcol >> 10;
                    const int rem   = gcol & 1023;
                    const int h     = rem >> 6;
                    const int d     = rem & 63;
                    if (which == 0) {
                        const size_t idx = (((size_t)(b * NHEAD + h)) * TT + t) * HDIM + d;
                        const float sv = vv * 0.125f;
                        const short hi = f2b(sv);
                        qh_[idx] = hi; ql_[idx] = f2b(sv - b2f(hi));
                    } else if (which == 1) {
                        const size_t idx = (((size_t)(b * NHEAD + h)) * TT + t) * HDIM + d;
                        const short hi = f2b(vv);
                        kh_[idx] = hi; kl_[idx] = f2b(vv - b2f(hi));
                    } else {
                        // V transposed-permuted: [bh][d][t']
                        const int t32 = t & 31;
                        const int u = t32 >> 4, gq = (t32 >> 2) & 3, rr = t32 & 3;
                        const int tp = (t & ~31) | (gq * 8 + u * 4 + rr);
                        const size_t idx = ((size_t)((b * NHEAD + h) * HDIM + d)) * TT + tp;
                        const short hi = f2b(vv);
                        vh_[idx] = hi; vl_[idx] = f2b(vv - b2f(hi));
                    }
                } else {
                    outF[(size_t)grow * N + gcol] = vv;
                }
            }
        }
    }
}

// ---------------------------------------------------------------------------
// MFMA attention v2 (validated round 4): swapped QK^T (P in registers),
// V^T from global, all staging via global_load_lds, double-buffered LDS.
// ---------------------------------------------------------------------------
__global__ __launch_bounds__(256, 2) void attn_mfma(
    const short* __restrict__ qh, const short* __restrict__ ql,
    const short* __restrict__ kh, const short* __restrict__ kl,
    const short* __restrict__ vth, const short* __restrict__ vtl,
    short* __restrict__ oh, short* __restrict__ ol)
{
    __shared__ short Kh_s[2][4096];
    __shared__ short Kl_s[2][4096];
    __shared__ short Vh_s[2][4096];
    __shared__ short Vl_s[2][4096];

    const int tid  = threadIdx.x;
    const int wid  = tid >> 6;
    const int lane = tid & 63;
    const int g    = lane >> 4;
    const int lr   = lane & 15;
    const int lr7  = lr & 7;

    const int bid = (blockIdx.x & 7) * (gridDim.x >> 3) + (blockIdx.x >> 3);
    const int bh  = bid >> 4;
    const int q0  = (bid & 15) * 128;
    const size_t base = (size_t)bh * TT * HDIM;

    short8 qhf[2][2], qlf[2][2];
#pragma unroll
    for (int qs = 0; qs < 2; ++qs) {
        const size_t qrow = base + (size_t)(q0 + wid * 32 + qs * 16 + lr) * HDIM;
#pragma unroll
        for (int ks = 0; ks < 2; ++ks) {
            qhf[qs][ks] = *(const short8*)(qh + qrow + ks * 32 + g * 8);
            qlf[qs][ks] = *(const short8*)(ql + qrow + ks * 32 + g * 8);
        }
    }

    f32x4 ofr[2][4];
#pragma unroll
    for (int qs = 0; qs < 2; ++qs)
#pragma unroll
        for (int dt = 0; dt < 4; ++dt) ofr[qs][dt] = (f32x4){0.f, 0.f, 0.f, 0.f};
    float lsum[2] = {0.f, 0.f};

    auto STAGE = [&](int bsel, int step) {
#pragma unroll
        for (int i = 0; i < 2; ++i) {
            const int c   = tid + i * 256;
            const int row = c >> 3;
            const int sl  = (c & 7) ^ (row & 7);
            const size_t srcK = base + (size_t)(step * 64 + row) * HDIM + sl * 8;
            const size_t srcV = ((size_t)(bh * HDIM + row)) * TT + step * 64 + sl * 8;
            gload_lds16(kh + srcK, &Kh_s[bsel][c * 8]);
            gload_lds16(kl + srcK, &Kl_s[bsel][c * 8]);
            gload_lds16(vth + srcV, &Vh_s[bsel][c * 8]);
            gload_lds16(vtl + srcV, &Vl_s[bsel][c * 8]);
        }
    };

    STAGE(0, 0);
    __syncthreads();

    for (int step = 0; step < TT / 64; ++step) {
        const int cur = step & 1;
        if (step + 1 < TT / 64) STAGE(cur ^ 1, step + 1);

        f32x4 sfr[4][2];
#pragma unroll
        for (int t = 0; t < 4; ++t)
#pragma unroll
            for (int qs = 0; qs < 2; ++qs) sfr[t][qs] = (f32x4){0.f, 0.f, 0.f, 0.f};
#pragma unroll
        for (int t = 0; t < 4; ++t) {
#pragma unroll
            for (int ks = 0; ks < 2; ++ks) {
                const int adr = (t * 16 + lr) * 64 + (((ks * 4 + g) ^ lr7) * 8);
                short8 k8h = *(const short8*)&Kh_s[cur][adr];
                short8 k8l = *(const short8*)&Kl_s[cur][adr];
#pragma unroll
                for (int qs = 0; qs < 2; ++qs) {
                    sfr[t][qs] = __builtin_amdgcn_mfma_f32_16x16x32_bf16(k8h, qhf[qs][ks], sfr[t][qs], 0, 0, 0);
                    sfr[t][qs] = __builtin_amdgcn_mfma_f32_16x16x32_bf16(k8l, qhf[qs][ks], sfr[t][qs], 0, 0, 0);
                    sfr[t][qs] = __builtin_amdgcn_mfma_f32_16x16x32_bf16(k8h, qlf[qs][ks], sfr[t][qs], 0, 0, 0);
                }
            }
        }

        short8 pah[2][2], pal[2][2];
#pragma unroll
        for (int qs = 0; qs < 2; ++qs)
#pragma unroll
            for (int ks = 0; ks < 2; ++ks)
#pragma unroll
                for (int t2 = 0; t2 < 2; ++t2) {
                    const int t = ks * 2 + t2;
#pragma unroll
                    for (int r = 0; r < 4; ++r) {
                        const float p = __expf(sfr[t][qs][r]);
                        lsum[qs] += p;
                        const short hi = f2b(p);
                        pah[qs][ks][t2 * 4 + r] = hi;
                        pal[qs][ks][t2 * 4 + r] = f2b(p - b2f(hi));
                    }
                }

#pragma unroll
        for (int dt = 0; dt < 4; ++dt) {
#pragma unroll
            for (int ks = 0; ks < 2; ++ks) {
                const int adr = (dt * 16 + lr) * 64 + (((ks * 4 + g) ^ lr7) * 8);
                short8 v8h = *(const short8*)&Vh_s[cur][adr];
                short8 v8l = *(const short8*)&Vl_s[cur][adr];
#pragma unroll
                for (int qs = 0; qs < 2; ++qs) {
                    ofr[qs][dt] = __builtin_amdgcn_mfma_f32_16x16x32_bf16(pah[qs][ks], v8h, ofr[qs][dt], 0, 0, 0);
                    ofr[qs][dt] = __builtin_amdgcn_mfma_f32_16x16x32_bf16(pal[qs][ks], v8h, ofr[qs][dt], 0, 0, 0);
                    ofr[qs][dt] = __builtin_amdgcn_mfma_f32_16x16x32_bf16(pah[qs][ks], v8l, ofr[qs][dt], 0, 0, 0);
                }
            }
        }
        __syncthreads();
    }

#pragma unroll
    for (int qs = 0; qs < 2; ++qs) {
        lsum[qs] += __shfl_xor(lsum[qs], 16, 64);
        lsum[qs] += __shfl_xor(lsum[qs], 32, 64);
    }
    float rl[2][4];
#pragma unroll
    for (int qs = 0; qs < 2; ++qs)
#pragma unroll
        for (int r = 0; r < 4; ++r)
            rl[qs][r] = 1.f / __shfl(lsum[qs], g * 4 + r, 64);

    const int b = bh >> 4, h = bh & 15;
#pragma unroll
    for (int qs = 0; qs < 2; ++qs)
#pragma unroll
        for (int r = 0; r < 4; ++r) {
            const int t = q0 + wid * 32 + qs * 16 + g * 4 + r;
#pragma unroll
            for (int dt = 0; dt < 4; ++dt) {
                const float v = ofr[qs][dt][r] * rl[qs][r];
                const short hi = f2b(v);
                const size_t off = ((size_t)b * TT + t) * DIM_C + h * HDIM + dt * 16 + lr;
                oh[off] = hi;
                ol[off] = f2b(v - b2f(hi));
            }
        }
}

// ---------------------------------------------------------------------------
extern "C" void kernel_launch(void* const* d_in, const int* in_sizes, int n_in,
                              void* d_out, int out_size, void* d_ws, size_t ws_size,
                              hipStream_t stream)
{
    const float* x      = (const float*)d_in[0];
    const float* w_qkv  = (const float*)d_in[1];
    const float* b_qkv  = (const float*)d_in[2];
    const float* w_proj = (const float*)d_in[3];
    const float* b_proj = (const float*)d_in[4];
    float* out = (float*)d_out;

    char* wsb = (char*)d_ws;
    const size_t MB = 1024 * 1024;
    short* xh_w = (short*)(wsb + 0 * MB);
    short* xl_w = (short*)(wsb + 8 * MB);
    short* oh_w = xh_w;
    short* ol_w = xl_w;
    short* wqTh = (short*)(wsb + 16 * MB);
    short* wqTl = (short*)(wsb + 22 * MB);
    short* wpTh = (short*)(wsb + 16 * MB);
    short* wpTl = (short*)(wsb + 18 * MB);
    short* qh_w = (short*)(wsb + 28 * MB);
    short* ql_w = (short*)(wsb + 36 * MB);
    short* kh_w = (short*)(wsb + 44 * MB);
    short* kl_w = (short*)(wsb + 52 * MB);
    short* vth_w = (short*)(wsb + 60 * MB);
    short* vtl_w = (short*)(wsb + 68 * MB);

    split_f32<<<dim3(NELEM / 4 / 256), 256, 0, stream>>>(x, xh_w, xl_w, NELEM / 4);
    transpose_split<<<dim3(3 * DIM_C / 32, DIM_C / 32), 256, 0, stream>>>(
        w_qkv, wqTh, wqTl, DIM_C, 3 * DIM_C);

    dim3 g1(3 * DIM_C / 128, BB * TT / 128);
    gemm_mfma<0><<<g1, 512, 0, stream>>>(xh_w, xl_w, wqTh, wqTl, b_qkv, nullptr,
                                         qh_w, ql_w, kh_w, kl_w, vth_w, vtl_w,
                                         BB * TT, 3 * DIM_C, DIM_C);

    transpose_split<<<dim3(DIM_C / 32, DIM_C / 32), 256, 0, stream>>>(
        w_proj, wpTh, wpTl, DIM_C, DIM_C);

    attn_mfma<<<dim3(512), 256, 0, stream>>>(
        qh_w, ql_w, kh_w, kl_w, vth_w, vtl_w, oh_w, ol_w);

    dim3 g2(DIM_C / 128, BB * TT / 128);
    gemm_mfma<1><<<g2, 512, 0, stream>>>(oh_w, ol_w, wpTh, wpTl, b_proj, out,
                                         nullptr, nullptr, nullptr, nullptr, nullptr, nullptr,
                                         BB * TT, DIM_C, DIM_C);
}

// Round 6
// 347.388 us; speedup vs baseline: 1.0223x; 1.0223x over previous
//
#include <hip/hip_runtime.h>

typedef __attribute__((ext_vector_type(8))) short short8;
typedef __attribute__((ext_vector_type(4))) float f32x4;

#define DIM_C 1024
#define NHEAD 16
#define HDIM  64
#define BB    2
#define TT    2048
#define NELEM ((size_t)BB * NHEAD * TT * HDIM)   // 4194304 per tensor

// ---- bf16 helpers (bit-level, RNE) ----------------------------------------
__device__ __forceinline__ short f2b(float f) {
    union { float f; unsigned u; } c; c.f = f;
    unsigned r = c.u + 0x7FFFu + ((c.u >> 16) & 1u);
    return (short)(r >> 16);
}
__device__ __forceinline__ float b2f(short s) {
    union { unsigned u; float f; } c; c.u = ((unsigned)(unsigned short)s) << 16;
    return c.f;
}
__device__ __forceinline__ void gload_lds16(const short* g, short* l) {
    __builtin_amdgcn_global_load_lds(
        (const __attribute__((address_space(1))) unsigned int*)g,
        (__attribute__((address_space(3))) unsigned int*)l, 16, 0, 0);
}

// ---------------------------------------------------------------------------
// Pre-pass 1: elementwise fp32 -> split bf16 (hi + lo)
// ---------------------------------------------------------------------------
__global__ __launch_bounds__(256) void split_f32(const float* __restrict__ X,
                                                 short* __restrict__ H,
                                                 short* __restrict__ L, int n4)
{
    const int i = blockIdx.x * 256 + threadIdx.x;
    if (i >= n4) return;
    float4 v = ((const float4*)X)[i];
    short h0 = f2b(v.x), h1 = f2b(v.y), h2 = f2b(v.z), h3 = f2b(v.w);
    short l0 = f2b(v.x - b2f(h0)), l1 = f2b(v.y - b2f(h1));
    short l2 = f2b(v.z - b2f(h2)), l3 = f2b(v.w - b2f(h3));
    typedef __attribute__((ext_vector_type(4))) short short4v;
    ((short4v*)H)[i] = (short4v){h0, h1, h2, h3};
    ((short4v*)L)[i] = (short4v){l0, l1, l2, l3};
}

// ---------------------------------------------------------------------------
// Pre-pass 2: W (K x N) fp32 -> W^T (N x K) split bf16, 32x32 LDS transpose
// ---------------------------------------------------------------------------
__global__ __launch_bounds__(256) void transpose_split(const float* __restrict__ W,
                                                       short* __restrict__ Th,
                                                       short* __restrict__ Tl,
                                                       int K, int N)
{
    __shared__ float T[32][33];
    const int tx = threadIdx.x & 31, ty = threadIdx.x >> 5;   // 32 x 8
    const int n0 = blockIdx.x * 32, k0 = blockIdx.y * 32;
#pragma unroll
    for (int i = 0; i < 4; ++i)
        T[ty + i * 8][tx] = W[(size_t)(k0 + ty + i * 8) * N + n0 + tx];
    __syncthreads();
#pragma unroll
    for (int i = 0; i < 4; ++i) {
        const int n = ty + i * 8;
        const float v = T[tx][n];
        const short hi = f2b(v);
        Th[(size_t)(n0 + n) * K + k0 + tx] = hi;
        Tl[(size_t)(n0 + n) * K + k0 + tx] = f2b(v - b2f(hi));
    }
}

// ---------------------------------------------------------------------------
// Split-bf16 MFMA GEMM v3: m201-style fine phases.
// 128x128 tile, 256 thr = 4 waves of 64x64 (2x2), BK=32, dbuf (64 KB LDS,
// 2 blocks/CU). Per K-tile: 4 phases (one m-slice each, 12 MFMA); phase 0
// also reads all B-frags; staging gloads for tile t+1 issued in phases 0-1
// (>=2 phases of latency cover); vmcnt(0) folded into phase 3 after MFMA;
// trailing phase barrier doubles as tile boundary. setprio around MFMA.
// ---------------------------------------------------------------------------
template <int EPI>
__global__ __launch_bounds__(256, 2) void gemm_mfma(
    const short* __restrict__ Ah, const short* __restrict__ Al,
    const short* __restrict__ BTh, const short* __restrict__ BTl,
    const float* __restrict__ bias,
    float* __restrict__ outF,
    short* __restrict__ qh_, short* __restrict__ ql_,
    short* __restrict__ kh_, short* __restrict__ kl_,
    short* __restrict__ vh_, short* __restrict__ vl_,
    int M, int N, int K)
{
    __shared__ short As_h[2][4096];   // 128 rows x 32 (BK) shorts = 8 KB / buf
    __shared__ short As_l[2][4096];
    __shared__ short Bs_h[2][4096];
    __shared__ short Bs_l[2][4096];

    const int tid  = threadIdx.x;
    const int lane = tid & 63;
    const int wid  = tid >> 6;
    const int wr   = wid >> 1, wc = wid & 1;   // 2x2 waves, tile 64x64
    const int g    = lane >> 4, lr = lane & 15;
    const int row0 = blockIdx.y * 128;
    const int col0 = blockIdx.x * 128;
    const int KT   = K >> 5;

    // staging: per array 512 chunks of 16B (128 rows x 4 slots); this thread
    // owns chunks c0=tid and c1=tid+256 (wave-contiguous LDS dests).
    const int c0 = tid, c1 = tid + 256;
    const int r0 = c0 >> 2, ss0 = (c0 & 3) ^ (r0 & 3);
    const int r1 = c1 >> 2, ss1 = (c1 & 3) ^ (r1 & 3);
    const size_t srcA0 = (size_t)(row0 + r0) * K + ss0 * 8;
    const size_t srcA1 = (size_t)(row0 + r1) * K + ss1 * 8;
    const size_t srcB0 = (size_t)(col0 + r0) * K + ss0 * 8;
    const size_t srcB1 = (size_t)(col0 + r1) * K + ss1 * 8;

    f32x4 acc[4][4];
#pragma unroll
    for (int m = 0; m < 4; ++m)
#pragma unroll
        for (int n = 0; n < 4; ++n) acc[m][n] = (f32x4){0.f, 0.f, 0.f, 0.f};

    // B-frag LDS addresses (per n), A-frag per phase
    int badr[4];
#pragma unroll
    for (int n = 0; n < 4; ++n) {
        const int r = wc * 64 + n * 16 + lr;
        badr[n] = (r * 4 + (g ^ (r & 3))) * 8;
    }
    int aadr[4];
#pragma unroll
    for (int p = 0; p < 4; ++p) {
        const int r = wr * 64 + p * 16 + lr;
        aadr[p] = (r * 4 + (g ^ (r & 3))) * 8;
    }

    // prologue: stage tile 0 into buf 0
    gload_lds16(Ah  + srcA0, &As_h[0][c0 * 8]);
    gload_lds16(Ah  + srcA1, &As_h[0][c1 * 8]);
    gload_lds16(Al  + srcA0, &As_l[0][c0 * 8]);
    gload_lds16(Al  + srcA1, &As_l[0][c1 * 8]);
    gload_lds16(BTh + srcB0, &Bs_h[0][c0 * 8]);
    gload_lds16(BTh + srcB1, &Bs_h[0][c1 * 8]);
    gload_lds16(BTl + srcB0, &Bs_l[0][c0 * 8]);
    gload_lds16(BTl + srcB1, &Bs_l[0][c1 * 8]);
    asm volatile("s_waitcnt vmcnt(0)" ::: "memory");
    __builtin_amdgcn_sched_barrier(0);
    __builtin_amdgcn_s_barrier();
    __builtin_amdgcn_sched_barrier(0);

    for (int t = 0; t < KT; ++t) {
        const int cur = t & 1;
        const int kn  = (t + 1) * 32;
        const bool more = (t + 1 < KT);
        short8 bh[4], bl[4];

#pragma unroll
        for (int p = 0; p < 4; ++p) {
            // --- ds_reads for this phase ---
            if (p == 0) {
#pragma unroll
                for (int n = 0; n < 4; ++n) {
                    bh[n] = *(const short8*)&Bs_h[cur][badr[n]];
                    bl[n] = *(const short8*)&Bs_l[cur][badr[n]];
                }
            }
            short8 ah = *(const short8*)&As_h[cur][aadr[p]];
            short8 al = *(const short8*)&As_l[cur][aadr[p]];

            // --- staging for tile t+1 (phases 0-1 only) ---
            if (p == 0 && more) {
                gload_lds16(Ah + srcA0 + kn, &As_h[cur ^ 1][c0 * 8]);
                gload_lds16(Ah + srcA1 + kn, &As_h[cur ^ 1][c1 * 8]);
                gload_lds16(Al + srcA0 + kn, &As_l[cur ^ 1][c0 * 8]);
                gload_lds16(Al + srcA1 + kn, &As_l[cur ^ 1][c1 * 8]);
            }
            if (p == 1 && more) {
                gload_lds16(BTh + srcB0 + kn, &Bs_h[cur ^ 1][c0 * 8]);
                gload_lds16(BTh + srcB1 + kn, &Bs_h[cur ^ 1][c1 * 8]);
                gload_lds16(BTl + srcB0 + kn, &Bs_l[cur ^ 1][c0 * 8]);
                gload_lds16(BTl + srcB1 + kn, &Bs_l[cur ^ 1][c1 * 8]);
            }

            __builtin_amdgcn_s_barrier();
            asm volatile("s_waitcnt lgkmcnt(0)" ::: "memory");
            __builtin_amdgcn_sched_barrier(0);
            __builtin_amdgcn_s_setprio(1);
#pragma unroll
            for (int n = 0; n < 4; ++n) {
                acc[p][n] = __builtin_amdgcn_mfma_f32_16x16x32_bf16(ah, bh[n], acc[p][n], 0, 0, 0);
                acc[p][n] = __builtin_amdgcn_mfma_f32_16x16x32_bf16(al, bh[n], acc[p][n], 0, 0, 0);
                acc[p][n] = __builtin_amdgcn_mfma_f32_16x16x32_bf16(ah, bl[n], acc[p][n], 0, 0, 0);
            }
            __builtin_amdgcn_s_setprio(0);
            __builtin_amdgcn_sched_barrier(0);
            if (p == 3) {
                // tile t+1 loads aged >= 2 phases; wait + boundary sync
                asm volatile("s_waitcnt vmcnt(0)" ::: "memory");
                __builtin_amdgcn_sched_barrier(0);
            }
            __builtin_amdgcn_s_barrier();
            __builtin_amdgcn_sched_barrier(0);
        }
    }

    // --- epilogue (identical to validated round-4 mapping) ---
#pragma unroll
    for (int m = 0; m < 4; ++m) {
#pragma unroll
        for (int n = 0; n < 4; ++n) {
#pragma unroll
            for (int r = 0; r < 4; ++r) {
                const int grow = row0 + wr * 64 + m * 16 + g * 4 + r;
                const int gcol = col0 + wc * 64 + n * 16 + lr;
                const float vv = acc[m][n][r] + bias[gcol];
                if (EPI == 0) {
                    const int b     = grow / TT;
                    const int t     = grow % TT;
                    const int which = gcol >> 10;
                    const int rem   = gcol & 1023;
                    const int h     = rem >> 6;
                    const int d     = rem & 63;
                    if (which == 0) {
                        const size_t idx = (((size_t)(b * NHEAD + h)) * TT + t) * HDIM + d;
                        const float sv = vv * 0.125f;
                        const short hi = f2b(sv);
                        qh_[idx] = hi; ql_[idx] = f2b(sv - b2f(hi));
                    } else if (which == 1) {
                        const size_t idx = (((size_t)(b * NHEAD + h)) * TT + t) * HDIM + d;
                        const short hi = f2b(vv);
                        kh_[idx] = hi; kl_[idx] = f2b(vv - b2f(hi));
                    } else {
                        // V transposed-permuted: [bh][d][t']
                        const int t32 = t & 31;
                        const int u = t32 >> 4, gq = (t32 >> 2) & 3, rr = t32 & 3;
                        const int tp = (t & ~31) | (gq * 8 + u * 4 + rr);
                        const size_t idx = ((size_t)((b * NHEAD + h) * HDIM + d)) * TT + tp;
                        const short hi = f2b(vv);
                        vh_[idx] = hi; vl_[idx] = f2b(vv - b2f(hi));
                    }
                } else {
                    outF[(size_t)grow * N + gcol] = vv;
                }
            }
        }
    }
}

// ---------------------------------------------------------------------------
// MFMA attention v2 (validated round 4): swapped QK^T (P in registers),
// V^T from global, all staging via global_load_lds, double-buffered LDS.
// ---------------------------------------------------------------------------
__global__ __launch_bounds__(256, 2) void attn_mfma(
    const short* __restrict__ qh, const short* __restrict__ ql,
    const short* __restrict__ kh, const short* __restrict__ kl,
    const short* __restrict__ vth, const short* __restrict__ vtl,
    short* __restrict__ oh, short* __restrict__ ol)
{
    __shared__ short Kh_s[2][4096];
    __shared__ short Kl_s[2][4096];
    __shared__ short Vh_s[2][4096];
    __shared__ short Vl_s[2][4096];

    const int tid  = threadIdx.x;
    const int wid  = tid >> 6;
    const int lane = tid & 63;
    const int g    = lane >> 4;
    const int lr   = lane & 15;
    const int lr7  = lr & 7;

    const int bid = (blockIdx.x & 7) * (gridDim.x >> 3) + (blockIdx.x >> 3);
    const int bh  = bid >> 4;
    const int q0  = (bid & 15) * 128;
    const size_t base = (size_t)bh * TT * HDIM;

    short8 qhf[2][2], qlf[2][2];
#pragma unroll
    for (int qs = 0; qs < 2; ++qs) {
        const size_t qrow = base + (size_t)(q0 + wid * 32 + qs * 16 + lr) * HDIM;
#pragma unroll
        for (int ks = 0; ks < 2; ++ks) {
            qhf[qs][ks] = *(const short8*)(qh + qrow + ks * 32 + g * 8);
            qlf[qs][ks] = *(const short8*)(ql + qrow + ks * 32 + g * 8);
        }
    }

    f32x4 ofr[2][4];
#pragma unroll
    for (int qs = 0; qs < 2; ++qs)
#pragma unroll
        for (int dt = 0; dt < 4; ++dt) ofr[qs][dt] = (f32x4){0.f, 0.f, 0.f, 0.f};
    float lsum[2] = {0.f, 0.f};

    auto STAGE = [&](int bsel, int step) {
#pragma unroll
        for (int i = 0; i < 2; ++i) {
            const int c   = tid + i * 256;
            const int row = c >> 3;
            const int sl  = (c & 7) ^ (row & 7);
            const size_t srcK = base + (size_t)(step * 64 + row) * HDIM + sl * 8;
            const size_t srcV = ((size_t)(bh * HDIM + row)) * TT + step * 64 + sl * 8;
            gload_lds16(kh + srcK, &Kh_s[bsel][c * 8]);
            gload_lds16(kl + srcK, &Kl_s[bsel][c * 8]);
            gload_lds16(vth + srcV, &Vh_s[bsel][c * 8]);
            gload_lds16(vtl + srcV, &Vl_s[bsel][c * 8]);
        }
    };

    STAGE(0, 0);
    __syncthreads();

    for (int step = 0; step < TT / 64; ++step) {
        const int cur = step & 1;
        if (step + 1 < TT / 64) STAGE(cur ^ 1, step + 1);

        f32x4 sfr[4][2];
#pragma unroll
        for (int t = 0; t < 4; ++t)
#pragma unroll
            for (int qs = 0; qs < 2; ++qs) sfr[t][qs] = (f32x4){0.f, 0.f, 0.f, 0.f};
#pragma unroll
        for (int t = 0; t < 4; ++t) {
#pragma unroll
            for (int ks = 0; ks < 2; ++ks) {
                const int adr = (t * 16 + lr) * 64 + (((ks * 4 + g) ^ lr7) * 8);
                short8 k8h = *(const short8*)&Kh_s[cur][adr];
                short8 k8l = *(const short8*)&Kl_s[cur][adr];
#pragma unroll
                for (int qs = 0; qs < 2; ++qs) {
                    sfr[t][qs] = __builtin_amdgcn_mfma_f32_16x16x32_bf16(k8h, qhf[qs][ks], sfr[t][qs], 0, 0, 0);
                    sfr[t][qs] = __builtin_amdgcn_mfma_f32_16x16x32_bf16(k8l, qhf[qs][ks], sfr[t][qs], 0, 0, 0);
                    sfr[t][qs] = __builtin_amdgcn_mfma_f32_16x16x32_bf16(k8h, qlf[qs][ks], sfr[t][qs], 0, 0, 0);
                }
            }
        }

        short8 pah[2][2], pal[2][2];
#pragma unroll
        for (int qs = 0; qs < 2; ++qs)
#pragma unroll
            for (int ks = 0; ks < 2; ++ks)
#pragma unroll
                for (int t2 = 0; t2 < 2; ++t2) {
                    const int t = ks * 2 + t2;
#pragma unroll
                    for (int r = 0; r < 4; ++r) {
                        const float p = __expf(sfr[t][qs][r]);
                        lsum[qs] += p;
                        const short hi = f2b(p);
                        pah[qs][ks][t2 * 4 + r] = hi;
                        pal[qs][ks][t2 * 4 + r] = f2b(p - b2f(hi));
                    }
                }

#pragma unroll
        for (int dt = 0; dt < 4; ++dt) {
#pragma unroll
            for (int ks = 0; ks < 2; ++ks) {
                const int adr = (dt * 16 + lr) * 64 + (((ks * 4 + g) ^ lr7) * 8);
                short8 v8h = *(const short8*)&Vh_s[cur][adr];
                short8 v8l = *(const short8*)&Vl_s[cur][adr];
#pragma unroll
                for (int qs = 0; qs < 2; ++qs) {
                    ofr[qs][dt] = __builtin_amdgcn_mfma_f32_16x16x32_bf16(pah[qs][ks], v8h, ofr[qs][dt], 0, 0, 0);
                    ofr[qs][dt] = __builtin_amdgcn_mfma_f32_16x16x32_bf16(pal[qs][ks], v8h, ofr[qs][dt], 0, 0, 0);
                    ofr[qs][dt] = __builtin_amdgcn_mfma_f32_16x16x32_bf16(pah[qs][ks], v8l, ofr[qs][dt], 0, 0, 0);
                }
            }
        }
        __syncthreads();
    }

#pragma unroll
    for (int qs = 0; qs < 2; ++qs) {
        lsum[qs] += __shfl_xor(lsum[qs], 16, 64);
        lsum[qs] += __shfl_xor(lsum[qs], 32, 64);
    }
    float rl[2][4];
#pragma unroll
    for (int qs = 0; qs < 2; ++qs)
#pragma unroll
        for (int r = 0; r < 4; ++r)
            rl[qs][r] = 1.f / __shfl(lsum[qs], g * 4 + r, 64);

    const int b = bh >> 4, h = bh & 15;
#pragma unroll
    for (int qs = 0; qs < 2; ++qs)
#pragma unroll
        for (int r = 0; r < 4; ++r) {
            const int t = q0 + wid * 32 + qs * 16 + g * 4 + r;
#pragma unroll
            for (int dt = 0; dt < 4; ++dt) {
                const float v = ofr[qs][dt][r] * rl[qs][r];
                const short hi = f2b(v);
                const size_t off = ((size_t)b * TT + t) * DIM_C + h * HDIM + dt * 16 + lr;
                oh[off] = hi;
                ol[off] = f2b(v - b2f(hi));
            }
        }
}

// ---------------------------------------------------------------------------
extern "C" void kernel_launch(void* const* d_in, const int* in_sizes, int n_in,
                              void* d_out, int out_size, void* d_ws, size_t ws_size,
                              hipStream_t stream)
{
    const float* x      = (const float*)d_in[0];
    const float* w_qkv  = (const float*)d_in[1];
    const float* b_qkv  = (const float*)d_in[2];
    const float* w_proj = (const float*)d_in[3];
    const float* b_proj = (const float*)d_in[4];
    float* out = (float*)d_out;

    char* wsb = (char*)d_ws;
    const size_t MB = 1024 * 1024;
    short* xh_w = (short*)(wsb + 0 * MB);
    short* xl_w = (short*)(wsb + 8 * MB);
    short* oh_w = xh_w;
    short* ol_w = xl_w;
    short* wqTh = (short*)(wsb + 16 * MB);
    short* wqTl = (short*)(wsb + 22 * MB);
    short* wpTh = (short*)(wsb + 16 * MB);
    short* wpTl = (short*)(wsb + 18 * MB);
    short* qh_w = (short*)(wsb + 28 * MB);
    short* ql_w = (short*)(wsb + 36 * MB);
    short* kh_w = (short*)(wsb + 44 * MB);
    short* kl_w = (short*)(wsb + 52 * MB);
    short* vth_w = (short*)(wsb + 60 * MB);
    short* vtl_w = (short*)(wsb + 68 * MB);

    split_f32<<<dim3(NELEM / 4 / 256), 256, 0, stream>>>(x, xh_w, xl_w, NELEM / 4);
    transpose_split<<<dim3(3 * DIM_C / 32, DIM_C / 32), 256, 0, stream>>>(
        w_qkv, wqTh, wqTl, DIM_C, 3 * DIM_C);

    dim3 g1(3 * DIM_C / 128, BB * TT / 128);
    gemm_mfma<0><<<g1, 256, 0, stream>>>(xh_w, xl_w, wqTh, wqTl, b_qkv, nullptr,
                                         qh_w, ql_w, kh_w, kl_w, vth_w, vtl_w,
                                         BB * TT, 3 * DIM_C, DIM_C);

    transpose_split<<<dim3(DIM_C / 32, DIM_C / 32), 256, 0, stream>>>(
        w_proj, wpTh, wpTl, DIM_C, DIM_C);

    attn_mfma<<<dim3(512), 256, 0, stream>>>(
        qh_w, ql_w, kh_w, kl_w, vth_w, vtl_w, oh_w, ol_w);

    dim3 g2(DIM_C / 128, BB * TT / 128);
    gemm_mfma<1><<<g2, 256, 0, stream>>>(oh_w, ol_w, wpTh, wpTl, b_proj, out,
                                         nullptr, nullptr, nullptr, nullptr, nullptr, nullptr,
                                         BB * TT, DIM_C, DIM_C);
}